// Round 4
// baseline (196.445 us; speedup 1.0000x reference)
//
#include <hip/hip_runtime.h>
#include <hip/hip_bf16.h>

#define B_   16
#define CIN  256
#define COUT 256
#define HH   64
#define WW   64
#define WDIM 512
#define OH   128
#define OW   128

typedef __attribute__((ext_vector_type(8))) short short8;
typedef __attribute__((ext_vector_type(4))) float f32x4;

__device__ __forceinline__ unsigned short f2bf(float f) {
    __hip_bfloat16 h = __float2bfloat16(f);
    return *reinterpret_cast<unsigned short*>(&h);
}
__device__ __forceinline__ float bf2f(unsigned short u) {
    unsigned int t = ((unsigned int)u) << 16;
    return *reinterpret_cast<float*>(&t);
}

// ws layout: bytes [0..16640) float scratch (sumsq partials + styles)
//            byte 32768:  wb bf16 [16][256 o][256 i]       (2 MB)
//            byte 4 MiB:  y  bf16 [16][4096 px][256 o]     (33.5 MB)

__global__ __launch_bounds__(256) void k_styles(const float* __restrict__ w,
                                                const float* __restrict__ aw,
                                                const float* __restrict__ ab,
                                                float* __restrict__ ws) {
    int b = blockIdx.x, i = threadIdx.x;
    const float4* wr = (const float4*)(w + b * WDIM);
    const float4* ar = (const float4*)(aw + (size_t)i * WDIM);
    float acc = 0.f;
    #pragma unroll 4
    for (int k = 0; k < WDIM / 4; ++k) {
        float4 wv = wr[k], av = ar[k];
        acc += wv.x * av.x + wv.y * av.y + wv.z * av.z + wv.w * av.w;
    }
    const float wg = 0.04419417382415922f; // 1/sqrt(512)
    float st = acc * wg + ab[i];
    ws[64 + b * CIN + i] = st;
    __shared__ float sred[256];
    sred[i] = st * st;
    __syncthreads();
    for (int s = 128; s > 0; s >>= 1) {
        if (i < s) sred[i] += sred[i + s];
        __syncthreads();
    }
    if (i == 0) ws[b] = sred[0];
}

__global__ __launch_bounds__(64) void k_wb(const float* __restrict__ weight,
                                           const float* __restrict__ ws,
                                           unsigned short* __restrict__ wb) {
    int o = blockIdx.x, b = blockIdx.y, l = threadIdx.x;
    float tot = 0.f;
    #pragma unroll
    for (int j = 0; j < B_; ++j) tot += ws[j];
    float srs = rsqrtf(tot / (float)(B_ * CIN));
    float4 wk = *(const float4*)(weight + (size_t)o * CIN + l * 4);
    float ss = wk.x * wk.x + wk.y * wk.y + wk.z * wk.z + wk.w * wk.w;
    #pragma unroll
    for (int off = 32; off; off >>= 1) ss += __shfl_xor(ss, off);
    float wkn = rsqrtf(ss / (float)CIN);
    float4 st = *(const float4*)(ws + 64 + b * CIN + l * 4);
    float4 t;
    t.x = wk.x * wkn * st.x * srs;
    t.y = wk.y * wkn * st.y * srs;
    t.z = wk.z * wkn * st.z * srs;
    t.w = wk.w * wkn * st.w * srs;
    float s2 = t.x * t.x + t.y * t.y + t.z * t.z + t.w * t.w;
    #pragma unroll
    for (int off = 32; off; off >>= 1) s2 += __shfl_xor(s2, off);
    float dcoef = rsqrtf(s2 + 1e-8f);
    ushort4 pk;
    pk.x = f2bf(t.x * dcoef);
    pk.y = f2bf(t.y * dcoef);
    pk.z = f2bf(t.z * dcoef);
    pk.w = f2bf(t.w * dcoef);
    *(ushort4*)(wb + ((size_t)b * COUT + o) * CIN + l * 4) = pk;
}

// LDS xt: [64 px][256 i] bf16, i-block swizzle: u16 index =
//   px*256 + ((ib ^ (px&31))<<3) + (i&7),  ib = i>>3.
__global__ __launch_bounds__(256, 4) void k_conv2(const float* __restrict__ x,
                                                  const float* __restrict__ bias,
                                                  const unsigned short* __restrict__ wb,
                                                  unsigned short* __restrict__ y) {
    __shared__ __align__(16) unsigned short xt[WW * CIN]; // 32768 B
    const int r = blockIdx.x;
    const int b = blockIdx.y;
    const int tid = threadIdx.x;
    const int lane = tid & 63;

    // ---- stage: channel-pairs -> swizzled LDS (u32 writes) ----
    {
        const int c4 = tid & 15;        // px quad base = c4*4
        const int ig = tid >> 4;        // 0..15
        const float* xp = x + (size_t)b * CIN * (HH * WW) + (size_t)r * WW + c4 * 4;
        #pragma unroll
        for (int p = 0; p < 8; ++p) {
            const int i0 = p * 32 + ig * 2;           // even channel
            float4 v0 = *(const float4*)(xp + (size_t)i0 * (HH * WW));
            float4 v1 = *(const float4*)(xp + (size_t)(i0 + 1) * (HH * WW));
            const int ib = i0 >> 3, e = i0 & 7;
            #pragma unroll
            for (int j = 0; j < 4; ++j) {
                const int px = c4 * 4 + j;
                float f0 = (j == 0) ? v0.x : (j == 1) ? v0.y : (j == 2) ? v0.z : v0.w;
                float f1 = (j == 0) ? v1.x : (j == 1) ? v1.y : (j == 2) ? v1.z : v1.w;
                unsigned int pk = (unsigned int)f2bf(f0) | ((unsigned int)f2bf(f1) << 16);
                int idx = px * 256 + ((ib ^ (px & 31)) << 3) + e;
                *(unsigned int*)&xt[idx] = pk;
            }
        }
    }
    __syncthreads();

    const int wv = tid >> 6;        // 0..3
    const int px0 = wv * 16;
    const int lo = lane & 15, hi = lane >> 4;   // hi 0..3
    const int mypx = px0 + lo;

    // B fragments in registers: breg[ks] = xt[mypx][ks*32 + hi*8 .. +7]
    short8 breg[8];
    #pragma unroll
    for (int ks = 0; ks < 8; ++ks) {
        int ib = ks * 4 + hi;
        int idx = mypx * 256 + ((ib ^ (mypx & 31)) << 3);
        breg[ks] = *(const short8*)&xt[idx];
    }

    const unsigned short* wbp = wb + (size_t)b * COUT * CIN;
    unsigned short* yp = y + ((size_t)b * (HH * WW) + (size_t)r * WW + mypx) * COUT;

    #pragma unroll 2
    for (int mc = 0; mc < 16; ++mc) {
        const int m0 = mc * 16;
        f32x4 acc = {0.f, 0.f, 0.f, 0.f};
        #pragma unroll
        for (int ks = 0; ks < 8; ++ks) {
            short8 a = *(const short8*)(wbp + (size_t)(m0 + lo) * CIN + ks * 32 + hi * 8);
            acc = __builtin_amdgcn_mfma_f32_16x16x32_bf16(a, breg[ks], acc, 0, 0, 0);
        }
        // D: col(px)=lane&15, row(o)=hi*4+j
        float4 bs = *(const float4*)(bias + m0 + hi * 4);
        ushort4 pk;
        pk.x = f2bf(acc[0] + bs.x);
        pk.y = f2bf(acc[1] + bs.y);
        pk.z = f2bf(acc[2] + bs.z);
        pk.w = f2bf(acc[3] + bs.w);
        *(ushort4*)(yp + m0 + hi * 4) = pk;
    }
}

// Upsample: block (p, og, b): reads y rows p-1,p,p+1 for o-slice og*32..+31
// into LDS [3][64][34-pad], writes out rows 2p, 2p+1 for those 32 channels.
#define OPAD 34
__global__ __launch_bounds__(256, 4) void k_up2(const unsigned short* __restrict__ y,
                                                float* __restrict__ out) {
    __shared__ __align__(8) unsigned short yt[3 * WW * OPAD]; // 13056 B
    const int p = blockIdx.x;
    const int og = blockIdx.y;
    const int b = blockIdx.z;
    const int tid = threadIdx.x;
    const int o0 = og * 32;

    // ---- stage 3 rows x 64 w x 32 o (u32 = 2 o) ----
    {
        const int rows[3] = { max(p - 1, 0), p, min(p + 1, HH - 1) };
        #pragma unroll
        for (int k = 0; k < 12; ++k) {
            int idx = k * 256 + tid;        // u32 index in [3][64][16]
            int row = idx >> 10;
            int rem = idx & 1023;
            int w = rem >> 4;
            int ou = rem & 15;
            unsigned int v = *(const unsigned int*)
                (y + ((size_t)b * (HH * WW) + (size_t)rows[row] * WW + w) * COUT + o0 + 2 * ou);
            *(unsigned int*)&yt[(row * WW + w) * OPAD + 2 * ou] = v;
        }
    }
    __syncthreads();

    const int o = tid >> 3;   // 0..31
    const int q = tid & 7;    // 0..7 -> ow chunk q*16..+15
    const int w0 = q * 8;

    float r0[10], r1[10];
    #pragma unroll
    for (int widx = 0; widx < 10; ++widx) {
        int w = min(max(w0 - 1 + widx, 0), WW - 1);
        float a = bf2f(yt[(0 * WW + w) * OPAD + o]);
        float m = bf2f(yt[(1 * WW + w) * OPAD + o]);
        float c = bf2f(yt[(2 * WW + w) * OPAD + o]);
        r0[widx] = 0.25f * a + 0.75f * m;   // out row 2p
        r1[widx] = 0.75f * m + 0.25f * c;   // out row 2p+1
    }

    float* op = out + (((size_t)(b * COUT + o0 + o) * OH) + 2 * p) * OW + q * 16;
    #pragma unroll
    for (int s = 0; s < 4; ++s) {
        float4 v0, v1;
        const int h = s * 2;  // r-index base: out cols s*4.. use r[h..h+3]
        v0.x = 0.25f * r0[h]     + 0.75f * r0[h + 1];
        v0.y = 0.75f * r0[h + 1] + 0.25f * r0[h + 2];
        v0.z = 0.25f * r0[h + 1] + 0.75f * r0[h + 2];
        v0.w = 0.75f * r0[h + 2] + 0.25f * r0[h + 3];
        v1.x = 0.25f * r1[h]     + 0.75f * r1[h + 1];
        v1.y = 0.75f * r1[h + 1] + 0.25f * r1[h + 2];
        v1.z = 0.25f * r1[h + 1] + 0.75f * r1[h + 2];
        v1.w = 0.75f * r1[h + 2] + 0.25f * r1[h + 3];
        *(float4*)(op + s * 4) = v0;
        *(float4*)(op + OW + s * 4) = v1;
    }
}

extern "C" void kernel_launch(void* const* d_in, const int* in_sizes, int n_in,
                              void* d_out, int out_size, void* d_ws, size_t ws_size,
                              hipStream_t stream) {
    (void)in_sizes; (void)n_in; (void)out_size; (void)ws_size;
    const float* x      = (const float*)d_in[0];
    const float* w      = (const float*)d_in[1];
    const float* aw     = (const float*)d_in[2];
    const float* ab     = (const float*)d_in[3];
    const float* weight = (const float*)d_in[4];
    const float* bias   = (const float*)d_in[5];
    float* out = (float*)d_out;
    float* wsf = (float*)d_ws;
    unsigned short* wb = (unsigned short*)((char*)d_ws + 32768);
    unsigned short* y  = (unsigned short*)((char*)d_ws + (4u << 20));

    hipLaunchKernelGGL(k_styles, dim3(16), dim3(256), 0, stream, w, aw, ab, wsf);
    hipLaunchKernelGGL(k_wb, dim3(COUT, B_), dim3(64), 0, stream, weight, wsf, wb);
    hipLaunchKernelGGL(k_conv2, dim3(HH, B_), dim3(256), 0, stream, x, bias, wb, y);
    hipLaunchKernelGGL(k_up2, dim3(HH, 8, B_), dim3(256), 0, stream, y, out);
}

// Round 5
// 155.730 us; speedup vs baseline: 1.2614x; 1.2614x over previous
//
#include <hip/hip_runtime.h>
#include <hip/hip_bf16.h>

#define B_   16
#define CIN  256
#define COUT 256
#define HH   64
#define WW   64
#define WDIM 512
#define OH   128
#define OW   128

typedef __attribute__((ext_vector_type(8))) short short8;
typedef __attribute__((ext_vector_type(4))) float f32x4;

__device__ __forceinline__ unsigned short f2bf(float f) {
    __hip_bfloat16 h = __float2bfloat16(f);
    return *reinterpret_cast<unsigned short*>(&h);
}
__device__ __forceinline__ float bf2f(unsigned short u) {
    unsigned int t = ((unsigned int)u) << 16;
    return *reinterpret_cast<float*>(&t);
}

// ws layout: bytes [0..16640) float scratch (sumsq partials + styles)
//            byte 32768:  wb bf16 [16][256 o][256 i]        (2 MB)
//            byte 4 MiB:  y  bf16 [16][256 o][64][64]       (33.5 MB)

__global__ __launch_bounds__(256) void k_styles(const float* __restrict__ w,
                                                const float* __restrict__ aw,
                                                const float* __restrict__ ab,
                                                float* __restrict__ ws) {
    int b = blockIdx.x, i = threadIdx.x;
    const float4* wr = (const float4*)(w + b * WDIM);
    const float4* ar = (const float4*)(aw + (size_t)i * WDIM);
    float acc = 0.f;
    #pragma unroll 4
    for (int k = 0; k < WDIM / 4; ++k) {
        float4 wv = wr[k], av = ar[k];
        acc += wv.x * av.x + wv.y * av.y + wv.z * av.z + wv.w * av.w;
    }
    const float wg = 0.04419417382415922f; // 1/sqrt(512)
    float st = acc * wg + ab[i];
    ws[64 + b * CIN + i] = st;
    __shared__ float sred[256];
    sred[i] = st * st;
    __syncthreads();
    for (int s = 128; s > 0; s >>= 1) {
        if (i < s) sred[i] += sred[i + s];
        __syncthreads();
    }
    if (i == 0) ws[b] = sred[0];
}

__global__ __launch_bounds__(64) void k_wb(const float* __restrict__ weight,
                                           const float* __restrict__ ws,
                                           unsigned short* __restrict__ wb) {
    int o = blockIdx.x, b = blockIdx.y, l = threadIdx.x;
    float tot = 0.f;
    #pragma unroll
    for (int j = 0; j < B_; ++j) tot += ws[j];
    float srs = rsqrtf(tot / (float)(B_ * CIN));
    float4 wk = *(const float4*)(weight + (size_t)o * CIN + l * 4);
    float ss = wk.x * wk.x + wk.y * wk.y + wk.z * wk.z + wk.w * wk.w;
    #pragma unroll
    for (int off = 32; off; off >>= 1) ss += __shfl_xor(ss, off);
    float wkn = rsqrtf(ss / (float)CIN);
    float4 st = *(const float4*)(ws + 64 + b * CIN + l * 4);
    float4 t;
    t.x = wk.x * wkn * st.x * srs;
    t.y = wk.y * wkn * st.y * srs;
    t.z = wk.z * wkn * st.z * srs;
    t.w = wk.w * wkn * st.w * srs;
    float s2 = t.x * t.x + t.y * t.y + t.z * t.z + t.w * t.w;
    #pragma unroll
    for (int off = 32; off; off >>= 1) s2 += __shfl_xor(s2, off);
    float dcoef = rsqrtf(s2 + 1e-8f);
    ushort4 pk;
    pk.x = f2bf(t.x * dcoef);
    pk.y = f2bf(t.y * dcoef);
    pk.z = f2bf(t.z * dcoef);
    pk.w = f2bf(t.w * dcoef);
    *(ushort4*)(wb + ((size_t)b * COUT + o) * CIN + l * 4) = pk;
}

// Conv: block (r,b), 256 thr. Stage row r swizzled in LDS (1 barrier), B-frags
// into regs, stream 16 o-chunks of A from L2-hot wb, transpose each chunk
// through small dbuf LDS tile, store y[b][o][r][*] in 128B-contiguous runs.
__global__ __launch_bounds__(256, 4) void k_conv3(const float* __restrict__ x,
                                                  const float* __restrict__ bias,
                                                  const unsigned short* __restrict__ wb,
                                                  unsigned short* __restrict__ y) {
    __shared__ __align__(16) unsigned short xt[WW * CIN];   // 32768 B
    __shared__ __align__(16) unsigned short ylds[2][WW][20]; // 5120 B
    const int r = blockIdx.x;
    const int b = blockIdx.y;
    const int tid = threadIdx.x;
    const int lane = tid & 63;

    // ---- stage: channel-pairs -> swizzled LDS (u32 writes) ----
    // xt u16 index = px*256 + ((ib ^ (px&31))<<3) + (i&7),  ib = i>>3
    {
        const int c4 = tid & 15;        // px quad base = c4*4
        const int ig = tid >> 4;        // 0..15
        const float* xp = x + (size_t)b * CIN * (HH * WW) + (size_t)r * WW + c4 * 4;
        #pragma unroll
        for (int p = 0; p < 8; ++p) {
            const int i0 = p * 32 + ig * 2;           // even channel
            float4 v0 = *(const float4*)(xp + (size_t)i0 * (HH * WW));
            float4 v1 = *(const float4*)(xp + (size_t)(i0 + 1) * (HH * WW));
            const int ib = i0 >> 3, e = i0 & 7;
            #pragma unroll
            for (int j = 0; j < 4; ++j) {
                const int px = c4 * 4 + j;
                float f0 = (j == 0) ? v0.x : (j == 1) ? v0.y : (j == 2) ? v0.z : v0.w;
                float f1 = (j == 0) ? v1.x : (j == 1) ? v1.y : (j == 2) ? v1.z : v1.w;
                unsigned int pk = (unsigned int)f2bf(f0) | ((unsigned int)f2bf(f1) << 16);
                int idx = px * 256 + ((ib ^ (px & 31)) << 3) + e;
                *(unsigned int*)&xt[idx] = pk;
            }
        }
    }
    __syncthreads();

    const int wv = tid >> 6;        // 0..3
    const int px0 = wv * 16;
    const int lo = lane & 15, hi = lane >> 4;   // hi 0..3
    const int mypx = px0 + lo;

    // B fragments in registers: breg[ks] = xt[mypx][ks*32 + hi*8 .. +7]
    short8 breg[8];
    #pragma unroll
    for (int ks = 0; ks < 8; ++ks) {
        int ib = ks * 4 + hi;
        int idx = mypx * 256 + ((ib ^ (mypx & 31)) << 3);
        breg[ks] = *(const short8*)&xt[idx];
    }

    const unsigned short* wbp = wb + (size_t)b * COUT * CIN;
    unsigned short* yb = y + (size_t)b * COUT * (HH * WW) + (size_t)r * WW;
    const int co = tid >> 4;         // copy-out o' 0..15
    const int cp = (tid & 15) * 4;   // copy-out px base

    for (int mc = 0; mc < 16; ++mc) {
        const int m0 = mc * 16;
        f32x4 acc = {0.f, 0.f, 0.f, 0.f};
        #pragma unroll
        for (int ks = 0; ks < 8; ++ks) {
            short8 a = *(const short8*)(wbp + (size_t)(m0 + lo) * CIN + ks * 32 + hi * 8);
            acc = __builtin_amdgcn_mfma_f32_16x16x32_bf16(a, breg[ks], acc, 0, 0, 0);
        }
        // D: col(px)=lane&15, row(o')=hi*4+j  -> ylds[px][o'] (pad 20)
        float4 bs = *(const float4*)(bias + m0 + hi * 4);
        ushort4 pk;
        pk.x = f2bf(acc[0] + bs.x);
        pk.y = f2bf(acc[1] + bs.y);
        pk.z = f2bf(acc[2] + bs.z);
        pk.w = f2bf(acc[3] + bs.w);
        *(ushort4*)&ylds[mc & 1][mypx][hi * 4] = pk;
        __syncthreads();
        // copy-out: thread (co, cp): 16 threads x 8B = 128B contiguous per o-row
        ushort4 ov;
        ov.x = ylds[mc & 1][cp + 0][co];
        ov.y = ylds[mc & 1][cp + 1][co];
        ov.z = ylds[mc & 1][cp + 2][co];
        ov.w = ylds[mc & 1][cp + 3][co];
        *(ushort4*)(yb + (size_t)(m0 + co) * (HH * WW) + cp) = ov;
    }
}

// Upsample: half-wave (32 lanes) per (b, ch, p): reads y rows p-1,p,p+1 (L3-hot),
// writes out rows 2p, 2p+1. Block = 8 consecutive p for one (b,ch) ->
// 16 consecutive out rows = 8KB contiguous write run. No LDS, no barriers.
__global__ __launch_bounds__(256, 8) void k_up(const unsigned short* __restrict__ y,
                                               float* __restrict__ out) {
    const int tid = threadIdx.x;
    const int t = tid & 31;       // col pair index
    const int s = tid >> 5;       // task slot 0..7
    const int idx = blockIdx.x * 8 + s;
    const int p = idx & 63;
    const int ch = (idx >> 6) & 255;
    const int b = idx >> 14;

    const unsigned short* yb = y + (size_t)(b * COUT + ch) * (HH * WW);
    const int pm1 = max(p - 1, 0), pp1 = min(p + 1, HH - 1);
    unsigned int T  = *(const unsigned int*)(yb + pm1 * WW + 2 * t);
    unsigned int M  = *(const unsigned int*)(yb + p   * WW + 2 * t);
    unsigned int Bt = *(const unsigned int*)(yb + pp1 * WW + 2 * t);

    float tB = bf2f((unsigned short)(T & 0xffff)),  tC = bf2f((unsigned short)(T >> 16));
    float mB = bf2f((unsigned short)(M & 0xffff)),  mC = bf2f((unsigned short)(M >> 16));
    float bB = bf2f((unsigned short)(Bt & 0xffff)), bC = bf2f((unsigned short)(Bt >> 16));

    // out row 2p = 0.25*y[p-1] + 0.75*y[p]; out row 2p+1 = 0.75*y[p] + 0.25*y[p+1]
    float aB = 0.25f * tB + 0.75f * mB, aC = 0.25f * tC + 0.75f * mC;
    float eB = 0.75f * mB + 0.25f * bB, eC = 0.75f * mC + 0.25f * bC;

    // neighbor cols via shfl within 32-lane group
    float aA = __shfl_up(aC, 1, 32);   if (t == 0)  aA = aB;
    float aD = __shfl_down(aB, 1, 32); if (t == 31) aD = aC;
    float eA = __shfl_up(eC, 1, 32);   if (t == 0)  eA = eB;
    float eD = __shfl_down(eB, 1, 32); if (t == 31) eD = eC;

    float4 o0, o1;
    o0.x = 0.25f * aA + 0.75f * aB;
    o0.y = 0.75f * aB + 0.25f * aC;
    o0.z = 0.25f * aB + 0.75f * aC;
    o0.w = 0.75f * aC + 0.25f * aD;
    o1.x = 0.25f * eA + 0.75f * eB;
    o1.y = 0.75f * eB + 0.25f * eC;
    o1.z = 0.25f * eB + 0.75f * eC;
    o1.w = 0.75f * eC + 0.25f * eD;

    float* op = out + (size_t)(b * COUT + ch) * (OH * OW) + (2 * p) * OW + 4 * t;
    *(float4*)op = o0;
    *(float4*)(op + OW) = o1;
}

extern "C" void kernel_launch(void* const* d_in, const int* in_sizes, int n_in,
                              void* d_out, int out_size, void* d_ws, size_t ws_size,
                              hipStream_t stream) {
    (void)in_sizes; (void)n_in; (void)out_size; (void)ws_size;
    const float* x      = (const float*)d_in[0];
    const float* w      = (const float*)d_in[1];
    const float* aw     = (const float*)d_in[2];
    const float* ab     = (const float*)d_in[3];
    const float* weight = (const float*)d_in[4];
    const float* bias   = (const float*)d_in[5];
    float* out = (float*)d_out;
    float* wsf = (float*)d_ws;
    unsigned short* wb = (unsigned short*)((char*)d_ws + 32768);
    unsigned short* y  = (unsigned short*)((char*)d_ws + (4u << 20));

    hipLaunchKernelGGL(k_styles, dim3(16), dim3(256), 0, stream, w, aw, ab, wsf);
    hipLaunchKernelGGL(k_wb, dim3(COUT, B_), dim3(64), 0, stream, weight, wsf, wb);
    hipLaunchKernelGGL(k_conv3, dim3(HH, B_), dim3(256), 0, stream, x, bias, wb, y);
    hipLaunchKernelGGL(k_up, dim3(B_ * COUT * HH / 8), dim3(256), 0, stream, y, out);
}